// Round 12
// baseline (336.304 us; speedup 1.0000x reference)
//
#include <hip/hip_runtime.h>

typedef _Float16 half8 __attribute__((ext_vector_type(8)));
typedef float f32x4 __attribute__((ext_vector_type(4)));

#define B_ 4
#define C_ 64
#define N_ 8192
#define K_ 20
#define LCELL 8                   // per-(split,class) sorted list depth
#define NSPLIT 4
#define NCAND (16 * LCELL * NSPLIT)  // 512 candidates per query into refine
#define CNT_TOTAL (B_ * N_ * K_)  // 655360
#define BN_EPSF 1e-5f

// global_load_lds wrappers: LDS dest is wave-uniform base + lane*size;
// global src is PER-LANE (enables source-side swizzle, guide rule #21).
typedef const __attribute__((address_space(1))) unsigned int g_u32;
typedef __attribute__((address_space(3))) unsigned int l_u32;
#define GLOAD16(G, L) \
  __builtin_amdgcn_global_load_lds((g_u32*)(G), (l_u32*)(L), 16, 0, 0)
#define GLOAD4(G, L) \
  __builtin_amdgcn_global_load_lds((g_u32*)(G), (l_u32*)(L), 4, 0, 0)

__device__ __forceinline__ f32x4 max4(f32x4 a, f32x4 b) {
  f32x4 r;
  r.x = fmaxf(a.x, b.x); r.y = fmaxf(a.y, b.y);
  r.z = fmaxf(a.z, b.z); r.w = fmaxf(a.w, b.w);
  return r;
}
__device__ __forceinline__ f32x4 min4(f32x4 a, f32x4 b) {
  f32x4 r;
  r.x = fminf(a.x, b.x); r.y = fminf(a.y, b.y);
  r.z = fminf(a.z, b.z); r.w = fminf(a.w, b.w);
  return r;
}

// wave-wide i32 min: 4x DPP row_ror (VALU, no DS pipe) + ds_swizzle xor16 +
// shfl_xor 32. Chain latency ~half of the 6-deep ds_bpermute butterfly.
__device__ __forceinline__ int wave_min_i32(int m) {
  m = min(m, __builtin_amdgcn_update_dpp(m, m, 0x121, 0xf, 0xf, true));
  m = min(m, __builtin_amdgcn_update_dpp(m, m, 0x122, 0xf, 0xf, true));
  m = min(m, __builtin_amdgcn_update_dpp(m, m, 0x124, 0xf, 0xf, true));
  m = min(m, __builtin_amdgcn_update_dpp(m, m, 0x128, 0xf, 0xf, true));
  m = min(m, __builtin_amdgcn_ds_swizzle(m, 0x401F));  // xor 16
  m = min(m, __shfl_xor(m, 32, 64));                   // xor 32
  return m;
}

// ---- Kernel 1: transpose x -> xt (f32 + f16), per-point sq (f32+f64),
// y1 = xt*W1^T, y2 = xt*W2^T - y1. W row o==lane held in 128 VGPRs.
// sq is stored PRE-BIASED by +512 (knn key bias folded in; refine uses sqd).
__global__ __launch_bounds__(256) void prep_kernel(
    const float* __restrict__ x, const float* __restrict__ W,
    float* __restrict__ xt, _Float16* __restrict__ xt16,
    float* __restrict__ sq, double* __restrict__ sqd,
    float* __restrict__ y1, float* __restrict__ y2) {
  __shared__ float xs[64 * 68];  // [n][c], stride 68 (16B-aligned rows)
  int b = blockIdx.x >> 7;
  int n0 = (blockIdx.x & 127) * 64;
  int t = threadIdx.x;
  int lane = t & 63;
  int wv = t >> 6;
#pragma unroll
  for (int i = 0; i < 16; ++i) {
    int lin = i * 256 + t;
    int c = lin >> 6, j = lin & 63;
    xs[j * 68 + c] = x[((b * 64 + c) * N_) + n0 + j];
  }
  // W row o = lane into registers (L1/L2-hot, 32 KB total)
  float4 w1[16], w2[16];
  const float4* wr = (const float4*)(W + lane * 128);
#pragma unroll
  for (int u = 0; u < 16; ++u) {
    w1[u] = wr[u];
    w2[u] = wr[16 + u];
  }
  __syncthreads();
#pragma unroll 2
  for (int i = 0; i < 16; ++i) {
    int nl = i * 4 + wv;
    const float4* xr = (const float4*)&xs[nl * 68];
    float d1x = 0.f, d1y = 0.f, d1z = 0.f, d1w = 0.f;
    float d2x = 0.f, d2y = 0.f, d2z = 0.f, d2w = 0.f;
#pragma unroll
    for (int u = 0; u < 16; ++u) {
      float4 xv = xr[u];
      d1x = fmaf(xv.x, w1[u].x, d1x);
      d1y = fmaf(xv.y, w1[u].y, d1y);
      d1z = fmaf(xv.z, w1[u].z, d1z);
      d1w = fmaf(xv.w, w1[u].w, d1w);
      d2x = fmaf(xv.x, w2[u].x, d2x);
      d2y = fmaf(xv.y, w2[u].y, d2y);
      d2z = fmaf(xv.z, w2[u].z, d2z);
      d2w = fmaf(xv.w, w2[u].w, d2w);
    }
    float d1 = (d1x + d1y) + (d1z + d1w);
    float d2 = (d2x + d2y) + (d2z + d2w);
    int n = n0 + nl;
    y1[((b * N_) + n) * 64 + lane] = d1;
    y2[((b * N_) + n) * 64 + lane] = d2 - d1;
  }
#pragma unroll
  for (int i = 0; i < 16; ++i) {
    int lin = i * 256 + t;
    int c = lin & 63, nl = lin >> 6;
    float v = xs[nl * 68 + c];
    size_t o = ((size_t)(b * N_) + n0 + nl) * 64 + c;
    xt[o] = v;
    xt16[o] = (_Float16)v;
  }
  if (t < 64) {
    float s0 = 0.f, s1 = 0.f, s2 = 0.f, s3 = 0.f;
    double sd0 = 0.0, sd1 = 0.0, sd2 = 0.0, sd3 = 0.0;
#pragma unroll
    for (int c = 0; c < 64; c += 4) {
      float v0 = xs[t * 68 + c], v1 = xs[t * 68 + c + 1];
      float v2 = xs[t * 68 + c + 2], v3 = xs[t * 68 + c + 3];
      s0 = fmaf(v0, v0, s0);
      s1 = fmaf(v1, v1, s1);
      s2 = fmaf(v2, v2, s2);
      s3 = fmaf(v3, v3, s3);
      sd0 = fma((double)v0, (double)v0, sd0);
      sd1 = fma((double)v1, (double)v1, sd1);
      sd2 = fma((double)v2, (double)v2, sd2);
      sd3 = fma((double)v3, (double)v3, sd3);
    }
    sq[b * N_ + n0 + t] = ((s0 + s1) + (s2 + s3)) + 512.0f;  // pre-biased
    sqd[b * N_ + n0 + t] = (sd0 + sd1) + (sd2 + sd3);
  }
}

// ---- Kernel 2: MFMA distance scan, v8 = v7's gload_lds staging + 3-buffer
// COUNTED-vmcnt schedule (guide T3/T4): the R11 __syncthreads drained
// vmcnt(0) per chunk — including the loads just issued — exposing load
// latency (VALUBusy 80%, idle 20% = drain). v8: chunk c -> buf c%3
// (static idx); phase(c) = {STAGE(c+2) early; CONSUME(c);
// s_waitcnt vmcnt(3) [drains chunk c+1 only, 3 loads/stage uniform:
// 2x GLOAD16 panel + 1x GLOAD4 sq redundantly by all 4 waves — benign
// same-data race, keeps per-wave vmcnt exact]; raw s_barrier;
// sched_barrier(0) (rule #18)}. Loads get ~2 phases of slack. A buffer is
// re-staged exactly one barrier after its consume (WAR-safe). Epilogue
// drains vmcnt(0). LDS 25.3KB -> 6 blocks/CU (was 8; R5/R6 showed weak
// sensitivity above 4). Swizzle unchanged (rule #21 pair).
__global__ __launch_bounds__(256, 4) void knn_mfma_kernel(
    const _Float16* __restrict__ xt16, const float* __restrict__ sq,
    int* __restrict__ pidx) {
  __shared__ alignas(16) char bufB[3][8192];  // 4 tiles * 16 rows * 128B
  __shared__ float bufS[3][64];
  int t = threadIdx.x;
  int wave = t >> 6;
  int lane = t & 63;
  int col = lane & 15;
  int quad = lane >> 4;
  int blk = blockIdx.x;
  int split = blk & 3;
  int qt = (blk >> 2) & 127;
  int b = blk >> 9;
  int q0 = qt * 64 + wave * 16;
  size_t bbase = (size_t)b * N_;

  // A fragments: A[m=col][k=quad*8+j] -> query row q0+col
  const _Float16* arow = xt16 + (bbase + q0 + col) * 64;
  half8 A0 = *(const half8*)(arow + quad * 8);
  half8 A1 = *(const half8*)(arow + 32 + quad * 8);

  int dl[4][LCELL];
#pragma unroll
  for (int r = 0; r < 4; ++r)
#pragma unroll
    for (int j = 0; j < LCELL; ++j) dl[r][j] = 0x7fffffff;

#define PAIR_INSERT(accX, accY, sA, sB, CTB)                                 \
  {                                                                          \
    const int ctb_ = (CTB);                                                  \
    _Pragma("unroll") for (int r = 0; r < 4; ++r) {                          \
      float kA = fmaf((accX)[r], -2.0f, (sA));                               \
      float kB = fmaf((accY)[r], -2.0f, (sB));                               \
      int va = (__float_as_int(kA) & ~255) | ctb_;                           \
      int vb = (__float_as_int(kB) & ~255) | (ctb_ + 1);                     \
      int lo = min(va, vb), hi = max(va, vb);                                \
      int o0 = min(dl[r][0], lo);                                            \
      int o1 = min(min(dl[r][1], max(dl[r][0], lo)), hi);                    \
      int o2 = min(min(dl[r][2], max(dl[r][1], lo)), max(dl[r][0], hi));     \
      int o3 = min(min(dl[r][3], max(dl[r][2], lo)), max(dl[r][1], hi));     \
      int o4 = min(min(dl[r][4], max(dl[r][3], lo)), max(dl[r][2], hi));     \
      int o5 = min(min(dl[r][5], max(dl[r][4], lo)), max(dl[r][3], hi));     \
      int o6 = min(min(dl[r][6], max(dl[r][5], lo)), max(dl[r][4], hi));     \
      int o7 = min(min(dl[r][7], max(dl[r][6], lo)), max(dl[r][5], hi));     \
      dl[r][0] = o0; dl[r][1] = o1; dl[r][2] = o2; dl[r][3] = o3;            \
      dl[r][4] = o4; dl[r][5] = o5; dl[r][6] = o6; dl[r][7] = o7;            \
    }                                                                        \
  }

  int c0 = split * (N_ / NSPLIT);
  const _Float16* gpanel = xt16 + (bbase + c0) * 64;
  const float* spanel = sq + bbase + c0;

  // per-lane pre-swizzled source offset (bytes): LDS slot (r=lane>>3,
  // e=lane&7) receives global chunk e^(r&7) of row r.
  int soff = (lane >> 3) * 128 + (((lane & 7) ^ ((lane >> 3) & 7)) << 4);
  // per-lane read offsets (bytes, within a tile): content (row=col,
  // chunk q) lives at col*128 + (q^(col&7))*16. Second k-half = ^64.
  int rbo0 = col * 128 + (((quad) ^ (col & 7)) << 4);
  int rbo1 = rbo0 ^ 64;

#define STAGE(BUF, CH)                                                     \
  {                                                                        \
    const char* gt =                                                       \
        (const char*)gpanel + ((size_t)(CH)*64 + wave * 16) * 128;         \
    char* wb = &bufB[BUF][wave * 2048];                                    \
    GLOAD16(gt + soff, wb);                                                \
    GLOAD16(gt + 1024 + soff, wb + 1024);                                  \
    GLOAD4(spanel + (CH)*64 + lane, bufS[BUF]); /* all waves, redundant */ \
  }
#define CONSUME(BUF, CH)                                                   \
  {                                                                        \
    const char* lb = bufB[BUF];                                            \
    const float* sb = bufS[BUF];                                           \
    const f32x4 z = {0.f, 0.f, 0.f, 0.f};                                  \
    half8 F0 = *(const half8*)(lb + 0 * 2048 + rbo0);                      \
    half8 F1 = *(const half8*)(lb + 0 * 2048 + rbo1);                      \
    half8 G0 = *(const half8*)(lb + 1 * 2048 + rbo0);                      \
    half8 G1 = *(const half8*)(lb + 1 * 2048 + rbo1);                      \
    f32x4 a0 = __builtin_amdgcn_mfma_f32_16x16x32_f16(A0, F0, z, 0, 0, 0); \
    a0 = __builtin_amdgcn_mfma_f32_16x16x32_f16(A1, F1, a0, 0, 0, 0);      \
    f32x4 a1 = __builtin_amdgcn_mfma_f32_16x16x32_f16(A0, G0, z, 0, 0, 0); \
    a1 = __builtin_amdgcn_mfma_f32_16x16x32_f16(A1, G1, a1, 0, 0, 0);      \
    half8 H0 = *(const half8*)(lb + 2 * 2048 + rbo0);                      \
    half8 H1 = *(const half8*)(lb + 2 * 2048 + rbo1);                      \
    half8 I0 = *(const half8*)(lb + 3 * 2048 + rbo0);                      \
    half8 I1 = *(const half8*)(lb + 3 * 2048 + rbo1);                      \
    f32x4 a2 = __builtin_amdgcn_mfma_f32_16x16x32_f16(A0, H0, z, 0, 0, 0); \
    a2 = __builtin_amdgcn_mfma_f32_16x16x32_f16(A1, H1, a2, 0, 0, 0);      \
    f32x4 a3 = __builtin_amdgcn_mfma_f32_16x16x32_f16(A0, I0, z, 0, 0, 0); \
    a3 = __builtin_amdgcn_mfma_f32_16x16x32_f16(A1, I1, a3, 0, 0, 0);      \
    float s0 = sb[col], s1 = sb[16 + col];                                 \
    float s2 = sb[32 + col], s3 = sb[48 + col];                            \
    PAIR_INSERT(a0, a1, s0, s1, (CH)*4);                                   \
    PAIR_INSERT(a2, a3, s2, s3, (CH)*4 + 2);                               \
  }
#define WAITB3()                                            \
  asm volatile("s_waitcnt vmcnt(3)" ::: "memory");          \
  __builtin_amdgcn_s_barrier();                             \
  __builtin_amdgcn_sched_barrier(0);

  // prologue: stage chunks 0,1; full drain (chunks 0,1 + A0/A1 all ready)
  STAGE(0, 0);
  STAGE(1, 1);
  __syncthreads();

  // phases 0..29 (10 x 3, static buffer indices). Phase(c):
  // stage c+2 early; consume c; wait vmcnt(3) (drains chunk c+1); barrier.
  for (int ch = 0; ch < 30; ch += 3) {
    STAGE(2, ch + 2);
    CONSUME(0, ch);
    WAITB3();
    STAGE(0, ch + 3);
    CONSUME(1, ch + 1);
    WAITB3();
    STAGE(1, ch + 4);
    CONSUME(2, ch + 2);
    WAITB3();
  }
  // phase 30 (buf0): chunk 30 drained by phase 29's vmcnt(3)
  CONSUME(0, 30);
  asm volatile("s_waitcnt vmcnt(0)" ::: "memory");  // drain chunk 31
  __builtin_amdgcn_s_barrier();
  __builtin_amdgcn_sched_barrier(0);
  // phase 31 (buf1)
  CONSUME(1, 31);
#undef PAIR_INSERT
#undef STAGE
#undef CONSUME
#undef WAITB3

#pragma unroll
  for (int r = 0; r < 4; ++r) {
    int q = q0 + quad * 4 + r;
    int* o = pidx + (bbase + q) * NCAND + split * (16 * LCELL) + col * LCELL;
#pragma unroll
    for (int j = 0; j < LCELL; ++j) o[j] = dl[r][j];  // raw packed value
  }
}

// ---- Kernel 3: refinement v11 (R8 WIN, unchanged) — short-chain pops,
// two points per wave, DPP min-reduce, ballot-decoded indices (no slds).
__global__ __launch_bounds__(256) void refine_kernel(
    const float* __restrict__ xt, const double* __restrict__ sqd,
    const int* __restrict__ pidx, int* __restrict__ idxf) {
  __shared__ float qs[4][2][64];
  __shared__ double klds[4][2][32];
  int tid = threadIdx.x;
  int wave = tid >> 6, lane = tid & 63;
  int pA = blockIdx.x * 8 + wave * 2;  // even global point id
  int pB = pA + 1;
  int b = pA >> 13;  // pA,pB share batch (8-aligned block of points)
  size_t bbase = (size_t)b * N_;
  int plA = pA & (N_ - 1), plB = pB & (N_ - 1);

  // stage both query rows into LDS (lanes 0..15 -> A, 16..31 -> B)
  if (lane < 16) {
    ((f32x4*)qs[wave][0])[lane] = ((const f32x4*)(xt + (size_t)pA * 64))[lane];
  } else if (lane < 32) {
    int l = lane - 16;
    ((f32x4*)qs[wave][1])[l] = ((const f32x4*)(xt + (size_t)pB * 64))[l];
  }

  // stage 1: lane's cell (split=lane>>4, col=lane&15): 8 sorted values per
  // point. Self-exclude (single displacement -> one bubble pass each).
  const int* piA = pidx + (size_t)pA * NCAND + lane * 8;
  const int* piB = pidx + (size_t)pB * NCAND + lane * 8;
  int4 ca0 = *(const int4*)piA;
  int4 ca1 = *(const int4*)(piA + 4);
  int4 cb0 = *(const int4*)piB;
  int4 cb1 = *(const int4*)(piB + 4);
  int colsplit = (lane & 15) + (lane >> 4) * (N_ / NSPLIT);

  int uA0 = ca0.x, uA1 = ca0.y, uA2 = ca0.z, uA3 = ca0.w;
  int uA4 = ca1.x, uA5 = ca1.y, uA6 = ca1.z, uA7 = ca1.w;
  int uB0 = cb0.x, uB1 = cb0.y, uB2 = cb0.z, uB3 = cb0.w;
  int uB4 = cb1.x, uB5 = cb1.y, uB6 = cb1.z, uB7 = cb1.w;
#define EXCL(v, pl) if (((((v)&255) << 4) + colsplit) == (pl)) (v) = 0x7fffffff;
  EXCL(uA0, plA) EXCL(uA1, plA) EXCL(uA2, plA) EXCL(uA3, plA)
  EXCL(uA4, plA) EXCL(uA5, plA) EXCL(uA6, plA) EXCL(uA7, plA)
  EXCL(uB0, plB) EXCL(uB1, plB) EXCL(uB2, plB) EXCL(uB3, plB)
  EXCL(uB4, plB) EXCL(uB5, plB) EXCL(uB6, plB) EXCL(uB7, plB)
#undef EXCL
#define BUB(a, b_) { int lo_ = min(a, b_), hi_ = max(a, b_); a = lo_; b_ = hi_; }
  BUB(uA0, uA1) BUB(uA1, uA2) BUB(uA2, uA3) BUB(uA3, uA4)
  BUB(uA4, uA5) BUB(uA5, uA6) BUB(uA6, uA7)
  BUB(uB0, uB1) BUB(uB1, uB2) BUB(uB2, uB3) BUB(uB3, uB4)
  BUB(uB4, uB5) BUB(uB5, uB6) BUB(uB6, uB7)
#undef BUB

  // stage 2: 32 pops per chain, interleaved; ci decoded from ballot (no LDS)
  unsigned long long mylt = (1ull << lane) - 1;
  int myci = 0;
#pragma unroll
  for (int s = 0; s < 32; ++s) {
    int mA = wave_min_i32(uA0);
    int mB = wave_min_i32(uB0);
    bool eqA = (uA0 == mA);
    bool eqB = (uB0 == mB);
    unsigned long long balA = __ballot(eqA);
    unsigned long long balB = __ballot(eqB);
    int ownA = (int)__builtin_ctzll(balA);
    int ownB = (int)__builtin_ctzll(balB);
    int ciA = ((mA & 255) << 4) + (ownA & 15) + (ownA >> 4) * (N_ / NSPLIT);
    int ciB = ((mB & 255) << 4) + (ownB & 15) + (ownB >> 4) * (N_ / NSPLIT);
    if (lane == s) myci = ciA;
    if (lane == s + 32) myci = ciB;
    bool advA = eqA && ((balA & mylt) == 0);  // first owner pops chain A
    bool advB = eqB && ((balB & mylt) == 0);
    uA0 = advA ? uA1 : uA0; uA1 = advA ? uA2 : uA1;
    uA2 = advA ? uA3 : uA2; uA3 = advA ? uA4 : uA3;
    uA4 = advA ? uA5 : uA4; uA5 = advA ? uA6 : uA5;
    uA6 = advA ? uA7 : uA6; uA7 = advA ? 0x7fffffff : uA7;
    uB0 = advB ? uB1 : uB0; uB1 = advB ? uB2 : uB1;
    uB2 = advB ? uB3 : uB2; uB3 = advB ? uB4 : uB3;
    uB4 = advB ? uB5 : uB4; uB5 = advB ? uB6 : uB5;
    uB6 = advB ? uB7 : uB6; uB7 = advB ? 0x7fffffff : uB7;
  }

  // stage 3: lane<32 -> point A candidate lane; lane>=32 -> point B
  // candidate lane-32. Full 64-dim fp64 dot per lane (4 accums).
  int half = lane >> 5;
  int s32 = lane & 31;
  int ci = myci;
  const f32x4* cr = (const f32x4*)(xt + (bbase + ci) * 64);
  const f32x4* qr = (const f32x4*)qs[wave][half];
  double a0 = 0.0, a1 = 0.0, a2 = 0.0, a3 = 0.0;
#pragma unroll
  for (int t2 = 0; t2 < 16; ++t2) {
    f32x4 cv = cr[t2];
    f32x4 qv = qr[t2];  // ds_read_b128 broadcast within each half
    a0 = fma((double)cv.x, (double)qv.x, a0);
    a1 = fma((double)cv.y, (double)qv.y, a1);
    a2 = fma((double)cv.z, (double)qv.z, a2);
    a3 = fma((double)cv.w, (double)qv.w, a3);
  }
  double dot = (a0 + a1) + (a2 + a3);
  double kd = fma(dot, -2.0, sqd[bbase + ci]) + 1024.0;
  double kv = __longlong_as_double(
      (__double_as_longlong(kd) & ~0x1FFFLL) | (long long)ci);
  klds[wave][half][s32] = kv;

  // stage 4: rank-count over own half's 32 unique exact keys
  {
    const double* kl = klds[wave][half];
    int c0 = 0, c1 = 0, c2 = 0, c3 = 0;
#pragma unroll
    for (int t2 = 0; t2 < 32; t2 += 4) {
      c0 += (kl[t2] < kv) ? 1 : 0;
      c1 += (kl[t2 + 1] < kv) ? 1 : 0;
      c2 += (kl[t2 + 2] < kv) ? 1 : 0;
      c3 += (kl[t2 + 3] < kv) ? 1 : 0;
    }
    int rank = (c0 + c1) + (c2 + c3);
    int pdst = half ? pB : pA;
    if (rank < K_) idxf[(size_t)pdst * K_ + rank] = ci;
  }
}

// ---- Kernel 4: stats v2 (R9 WIN, unchanged) — 1-deep gather pipeline
// across the 4 points (double-buffered G regs; next point's L2 latency
// hides under the current reduce).
__global__ __launch_bounds__(256) void stats_kernel(
    const float* __restrict__ y1, const float* __restrict__ y2,
    const int* __restrict__ idxf, float* __restrict__ maxh,
    float* __restrict__ minh, float* __restrict__ gsum,
    float* __restrict__ gsq) {
  __shared__ float lsum[64], lsq[64];
  int tid = threadIdx.x;
  if (tid < 64) { lsum[tid] = 0.f; lsq[tid] = 0.f; }
  __syncthreads();
  int wv = tid >> 6, lane = tid & 63;
  int u = lane & 15, jb = lane >> 4;
  int p0 = blockIdx.x * 16 + wv * 4;  // 16 contiguous points per block
  size_t nb = (size_t)((p0 >> 13) * N_);
  f32x4 css = {0.f, 0.f, 0.f, 0.f}, cqq = {0.f, 0.f, 0.f, 0.f};

  // preload all 4 points' neighbor indices (independent loads)
  int idxv0 = (lane < K_) ? idxf[(size_t)(p0 + 0) * K_ + lane] : 0;
  int idxv1 = (lane < K_) ? idxf[(size_t)(p0 + 1) * K_ + lane] : 0;
  int idxv2 = (lane < K_) ? idxf[(size_t)(p0 + 2) * K_ + lane] : 0;
  int idxv3 = (lane < K_) ? idxf[(size_t)(p0 + 3) * K_ + lane] : 0;

  f32x4 Ga0, Ga1, Ga2, Ga3, Ga4;  // buffer A
  f32x4 Gb0, Gb1, Gb2, Gb3, Gb4;  // buffer B

#define ISSUE(B0_, B1_, B2_, B3_, B4_, IV)                                 \
  {                                                                        \
    int n0 = __shfl((IV), jb, 64);                                         \
    int n1 = __shfl((IV), jb + 4, 64);                                     \
    int n2 = __shfl((IV), jb + 8, 64);                                     \
    int n3 = __shfl((IV), jb + 12, 64);                                    \
    int n4 = __shfl((IV), jb + 16, 64);                                    \
    B0_ = ((const f32x4*)(y1 + (nb + n0) * 64))[u];                        \
    B1_ = ((const f32x4*)(y1 + (nb + n1) * 64))[u];                        \
    B2_ = ((const f32x4*)(y1 + (nb + n2) * 64))[u];                        \
    B3_ = ((const f32x4*)(y1 + (nb + n3) * 64))[u];                        \
    B4_ = ((const f32x4*)(y1 + (nb + n4) * 64))[u];                        \
  }
#define REDUCE(B0_, B1_, B2_, B3_, B4_, IT)                                \
  {                                                                        \
    int p = p0 + (IT);                                                     \
    f32x4 mx = B0_, mn = B0_, sm = B0_, s2 = B0_ * B0_;                    \
    mx = max4(mx, B1_); mn = min4(mn, B1_); sm += B1_; s2 += B1_ * B1_;    \
    mx = max4(mx, B2_); mn = min4(mn, B2_); sm += B2_; s2 += B2_ * B2_;    \
    mx = max4(mx, B3_); mn = min4(mn, B3_); sm += B3_; s2 += B3_ * B3_;    \
    mx = max4(mx, B4_); mn = min4(mn, B4_); sm += B4_; s2 += B4_ * B4_;    \
    _Pragma("unroll") for (int c = 0; c < 4; ++c) {                        \
      mx[c] = fmaxf(mx[c], __shfl_xor(mx[c], 16, 64));                     \
      mx[c] = fmaxf(mx[c], __shfl_xor(mx[c], 32, 64));                     \
      mn[c] = fminf(mn[c], __shfl_xor(mn[c], 16, 64));                     \
      mn[c] = fminf(mn[c], __shfl_xor(mn[c], 32, 64));                     \
      sm[c] += __shfl_xor(sm[c], 16, 64);                                  \
      sm[c] += __shfl_xor(sm[c], 32, 64);                                  \
      s2[c] += __shfl_xor(s2[c], 16, 64);                                  \
      s2[c] += __shfl_xor(s2[c], 32, 64);                                  \
    }                                                                      \
    if (jb == 0) {                                                         \
      f32x4 y2c = ((const f32x4*)(y2 + (size_t)p * 64))[u];                \
      ((f32x4*)(maxh + (size_t)p * 64))[u] = mx + y2c;                     \
      ((f32x4*)(minh + (size_t)p * 64))[u] = mn + y2c;                     \
      css += sm + 20.0f * y2c;                                             \
      cqq += s2 + 2.0f * y2c * sm + 20.0f * y2c * y2c;                     \
    }                                                                      \
  }

  ISSUE(Ga0, Ga1, Ga2, Ga3, Ga4, idxv0);        // point 0 -> A
  ISSUE(Gb0, Gb1, Gb2, Gb3, Gb4, idxv1);        // point 1 -> B (in flight)
  REDUCE(Ga0, Ga1, Ga2, Ga3, Ga4, 0);           // reduce 0 (hides 1's lat)
  ISSUE(Ga0, Ga1, Ga2, Ga3, Ga4, idxv2);        // point 2 -> A
  REDUCE(Gb0, Gb1, Gb2, Gb3, Gb4, 1);           // reduce 1 (hides 2's lat)
  ISSUE(Gb0, Gb1, Gb2, Gb3, Gb4, idxv3);        // point 3 -> B
  REDUCE(Ga0, Ga1, Ga2, Ga3, Ga4, 2);           // reduce 2 (hides 3's lat)
  REDUCE(Gb0, Gb1, Gb2, Gb3, Gb4, 3);           // reduce 3
#undef ISSUE
#undef REDUCE

  if (jb == 0) {
#pragma unroll
    for (int c = 0; c < 4; ++c) {
      atomicAdd(&lsum[u * 4 + c], css[c]);
      atomicAdd(&lsq[u * 4 + c], cqq[c]);
    }
  }
  __syncthreads();
  if (tid < 64) {
    atomicAdd(&gsum[tid], lsum[tid]);
    atomicAdd(&gsq[tid], lsq[tid]);
  }
}

// ---- Kernel 5: affine + relu + max-over-k selection, transposed store.
// v2: pointer-select (single load) instead of ternary over two loads.
__global__ __launch_bounds__(256) void final_kernel(
    const float* __restrict__ maxh, const float* __restrict__ minh,
    const float* __restrict__ gsum, const float* __restrict__ gsq,
    const float* __restrict__ gamma, const float* __restrict__ beta,
    float* __restrict__ out) {
  __shared__ float sc[64], cc_[64];
  __shared__ float tile[64 * 65];
  int b = blockIdx.x >> 7;
  int n0 = (blockIdx.x & 127) * 64;
  int t = threadIdx.x;
  if (t < 64) {
    float mean = gsum[t] * (1.0f / CNT_TOTAL);
    float var = gsq[t] * (1.0f / CNT_TOTAL) - mean * mean;
    float s = gamma[t] * rsqrtf(var + BN_EPSF);
    sc[t] = s;
    cc_[t] = beta[t] - mean * s;
  }
  __syncthreads();
#pragma unroll
  for (int i = 0; i < 16; ++i) {
    int lin = i * 256 + t;
    int o = lin & 63, nl = lin >> 6;
    size_t off = ((size_t)(b * N_) + n0 + nl) * 64 + o;
    float s = sc[o];
    const float* src = (s >= 0.f) ? maxh : minh;  // pointer select, 1 load
    float val = fmaxf(fmaf(src[off], s, cc_[o]), 0.f);
    tile[o * 65 + nl] = val;
  }
  __syncthreads();
#pragma unroll
  for (int i = 0; i < 16; ++i) {
    int lin = i * 256 + t;
    int nl = lin & 63, o = lin >> 6;
    out[((size_t)(b * 64) + o) * N_ + n0 + nl] = tile[o * 65 + nl];
  }
}

extern "C" void kernel_launch(void* const* d_in, const int* in_sizes, int n_in,
                              void* d_out, int out_size, void* d_ws,
                              size_t ws_size, hipStream_t stream) {
  const float* x = (const float*)d_in[0];
  const float* W = (const float*)d_in[1];
  const float* gamma = (const float*)d_in[2];
  const float* beta = (const float*)d_in[3];
  float* out = (float*)d_out;

  char* ws = (char*)d_ws;
  size_t off = 0;
  auto alloc = [&](size_t bytes) {
    char* p = ws + off;
    off += (bytes + 255) & ~(size_t)255;
    return p;
  };
  float* xt = (float*)alloc((size_t)B_ * N_ * 64 * 4);
  _Float16* xt16 = (_Float16*)alloc((size_t)B_ * N_ * 64 * 2);
  float* y1 = (float*)alloc((size_t)B_ * N_ * 64 * 4);
  float* y2 = (float*)alloc((size_t)B_ * N_ * 64 * 4);
  float* sq = (float*)alloc((size_t)B_ * N_ * 4);
  double* sqd = (double*)alloc((size_t)B_ * N_ * 8);
  int* pidx = (int*)alloc((size_t)B_ * N_ * NCAND * 4);  // 67 MB
  float* maxh = (float*)alloc((size_t)B_ * N_ * 64 * 4);
  int* idxf = (int*)alloc((size_t)B_ * N_ * K_ * 4);
  float* gsum = (float*)alloc(256);
  float* gsq = (float*)alloc(256);
  // minh aliases pidx (pidx fully consumed by refine before stats runs)
  float* minh = (float*)pidx;

  hipMemsetAsync(gsum, 0, 256, stream);
  hipMemsetAsync(gsq, 0, 256, stream);

  prep_kernel<<<B_ * (N_ / 64), 256, 0, stream>>>(x, W, xt, xt16, sq, sqd,
                                                  y1, y2);
  knn_mfma_kernel<<<B_ * (N_ / 64) * NSPLIT, 256, 0, stream>>>(xt16, sq, pidx);
  refine_kernel<<<(B_ * N_) / 8, 256, 0, stream>>>(xt, sqd, pidx, idxf);
  stats_kernel<<<(B_ * N_) / 16, 256, 0, stream>>>(y1, y2, idxf, maxh, minh,
                                                   gsum, gsq);
  final_kernel<<<B_ * (N_ / 64), 256, 0, stream>>>(maxh, minh, gsum, gsq,
                                                   gamma, beta, out);
}

// Round 14
// 334.435 us; speedup vs baseline: 1.0056x; 1.0056x over previous
//
#include <hip/hip_runtime.h>

typedef _Float16 half8 __attribute__((ext_vector_type(8)));
typedef float f32x4 __attribute__((ext_vector_type(4)));

#define B_ 4
#define C_ 64
#define N_ 8192
#define K_ 20
#define LCELL 8                   // per-(split,class) sorted list depth
#define NSPLIT 4
#define NCAND (16 * LCELL * NSPLIT)  // 512 candidates per query into refine
#define CNT_TOTAL (B_ * N_ * K_)  // 655360
#define BN_EPSF 1e-5f

// global_load_lds wrappers: LDS dest is wave-uniform base + lane*size;
// global src is PER-LANE (enables source-side swizzle, guide rule #21).
typedef const __attribute__((address_space(1))) unsigned int g_u32;
typedef __attribute__((address_space(3))) unsigned int l_u32;
#define GLOAD16(G, L) \
  __builtin_amdgcn_global_load_lds((g_u32*)(G), (l_u32*)(L), 16, 0, 0)
#define GLOAD4(G, L) \
  __builtin_amdgcn_global_load_lds((g_u32*)(G), (l_u32*)(L), 4, 0, 0)

__device__ __forceinline__ f32x4 max4(f32x4 a, f32x4 b) {
  f32x4 r;
  r.x = fmaxf(a.x, b.x); r.y = fmaxf(a.y, b.y);
  r.z = fmaxf(a.z, b.z); r.w = fmaxf(a.w, b.w);
  return r;
}
__device__ __forceinline__ f32x4 min4(f32x4 a, f32x4 b) {
  f32x4 r;
  r.x = fminf(a.x, b.x); r.y = fminf(a.y, b.y);
  r.z = fminf(a.z, b.z); r.w = fminf(a.w, b.w);
  return r;
}

// wave-wide i32 min: 4x DPP row_ror (VALU, no DS pipe) + ds_swizzle xor16 +
// shfl_xor 32. Chain latency ~half of the 6-deep ds_bpermute butterfly.
__device__ __forceinline__ int wave_min_i32(int m) {
  m = min(m, __builtin_amdgcn_update_dpp(m, m, 0x121, 0xf, 0xf, true));
  m = min(m, __builtin_amdgcn_update_dpp(m, m, 0x122, 0xf, 0xf, true));
  m = min(m, __builtin_amdgcn_update_dpp(m, m, 0x124, 0xf, 0xf, true));
  m = min(m, __builtin_amdgcn_update_dpp(m, m, 0x128, 0xf, 0xf, true));
  m = min(m, __builtin_amdgcn_ds_swizzle(m, 0x401F));  // xor 16
  m = min(m, __shfl_xor(m, 32, 64));                   // xor 32
  return m;
}

// ---- Kernel 1: transpose x -> xt (f32 + f16), per-point sq (f32+f64),
// y1 = xt*W1^T, y2 = xt*W2^T - y1. W row o==lane held in 128 VGPRs.
// sq is stored PRE-BIASED by +512 (knn key bias folded in; refine uses sqd).
__global__ __launch_bounds__(256) void prep_kernel(
    const float* __restrict__ x, const float* __restrict__ W,
    float* __restrict__ xt, _Float16* __restrict__ xt16,
    float* __restrict__ sq, double* __restrict__ sqd,
    float* __restrict__ y1, float* __restrict__ y2) {
  __shared__ float xs[64 * 68];  // [n][c], stride 68 (16B-aligned rows)
  int b = blockIdx.x >> 7;
  int n0 = (blockIdx.x & 127) * 64;
  int t = threadIdx.x;
  int lane = t & 63;
  int wv = t >> 6;
#pragma unroll
  for (int i = 0; i < 16; ++i) {
    int lin = i * 256 + t;
    int c = lin >> 6, j = lin & 63;
    xs[j * 68 + c] = x[((b * 64 + c) * N_) + n0 + j];
  }
  // W row o = lane into registers (L1/L2-hot, 32 KB total)
  float4 w1[16], w2[16];
  const float4* wr = (const float4*)(W + lane * 128);
#pragma unroll
  for (int u = 0; u < 16; ++u) {
    w1[u] = wr[u];
    w2[u] = wr[16 + u];
  }
  __syncthreads();
#pragma unroll 2
  for (int i = 0; i < 16; ++i) {
    int nl = i * 4 + wv;
    const float4* xr = (const float4*)&xs[nl * 68];
    float d1x = 0.f, d1y = 0.f, d1z = 0.f, d1w = 0.f;
    float d2x = 0.f, d2y = 0.f, d2z = 0.f, d2w = 0.f;
#pragma unroll
    for (int u = 0; u < 16; ++u) {
      float4 xv = xr[u];
      d1x = fmaf(xv.x, w1[u].x, d1x);
      d1y = fmaf(xv.y, w1[u].y, d1y);
      d1z = fmaf(xv.z, w1[u].z, d1z);
      d1w = fmaf(xv.w, w1[u].w, d1w);
      d2x = fmaf(xv.x, w2[u].x, d2x);
      d2y = fmaf(xv.y, w2[u].y, d2y);
      d2z = fmaf(xv.z, w2[u].z, d2z);
      d2w = fmaf(xv.w, w2[u].w, d2w);
    }
    float d1 = (d1x + d1y) + (d1z + d1w);
    float d2 = (d2x + d2y) + (d2z + d2w);
    int n = n0 + nl;
    y1[((b * N_) + n) * 64 + lane] = d1;
    y2[((b * N_) + n) * 64 + lane] = d2 - d1;
  }
#pragma unroll
  for (int i = 0; i < 16; ++i) {
    int lin = i * 256 + t;
    int c = lin & 63, nl = lin >> 6;
    float v = xs[nl * 68 + c];
    size_t o = ((size_t)(b * N_) + n0 + nl) * 64 + c;
    xt[o] = v;
    xt16[o] = (_Float16)v;
  }
  if (t < 64) {
    float s0 = 0.f, s1 = 0.f, s2 = 0.f, s3 = 0.f;
    double sd0 = 0.0, sd1 = 0.0, sd2 = 0.0, sd3 = 0.0;
#pragma unroll
    for (int c = 0; c < 64; c += 4) {
      float v0 = xs[t * 68 + c], v1 = xs[t * 68 + c + 1];
      float v2 = xs[t * 68 + c + 2], v3 = xs[t * 68 + c + 3];
      s0 = fmaf(v0, v0, s0);
      s1 = fmaf(v1, v1, s1);
      s2 = fmaf(v2, v2, s2);
      s3 = fmaf(v3, v3, s3);
      sd0 = fma((double)v0, (double)v0, sd0);
      sd1 = fma((double)v1, (double)v1, sd1);
      sd2 = fma((double)v2, (double)v2, sd2);
      sd3 = fma((double)v3, (double)v3, sd3);
    }
    sq[b * N_ + n0 + t] = ((s0 + s1) + (s2 + s3)) + 512.0f;  // pre-biased
    sqd[b * N_ + n0 + t] = (sd0 + sd1) + (sd2 + sd3);
  }
}

// ---- Kernel 2: MFMA distance scan, v7 (R11 form — BEST measured: 140us,
// pipeline 334.8). gload_lds width-16 staging (no VGPR round-trip, no
// ds_writes), double-buffered, 2 barriers/chunk-pair, 16.9KB LDS = 8
// blocks/CU. R12's 3-buffer counted-vmcnt variant measured knn -1us but
// pipeline +1.5us (LDS 25.6KB -> 6 blocks/CU) — reverted. LDS rows LINEAR
// 128B; source pre-swizzled chunk_pos = e^(row&7), read applies same XOR
// (rule #21). VALU-work pinned at ~112us-equiv across R5-R12: the
// pair-merge top-8 network is the algorithmic floor; residual ~20% idle is
// the 2-barrier structural overhead (R12 falsified the load-drain theory).
__global__ __launch_bounds__(256, 4) void knn_mfma_kernel(
    const _Float16* __restrict__ xt16, const float* __restrict__ sq,
    int* __restrict__ pidx) {
  __shared__ alignas(16) char bufB[2][8192];  // 4 tiles * 16 rows * 128B
  __shared__ float bufS[2][64];
  int t = threadIdx.x;
  int wave = t >> 6;
  int lane = t & 63;
  int col = lane & 15;
  int quad = lane >> 4;
  int blk = blockIdx.x;
  int split = blk & 3;
  int qt = (blk >> 2) & 127;
  int b = blk >> 9;
  int q0 = qt * 64 + wave * 16;
  size_t bbase = (size_t)b * N_;

  // A fragments: A[m=col][k=quad*8+j] -> query row q0+col
  const _Float16* arow = xt16 + (bbase + q0 + col) * 64;
  half8 A0 = *(const half8*)(arow + quad * 8);
  half8 A1 = *(const half8*)(arow + 32 + quad * 8);

  int dl[4][LCELL];
#pragma unroll
  for (int r = 0; r < 4; ++r)
#pragma unroll
    for (int j = 0; j < LCELL; ++j) dl[r][j] = 0x7fffffff;

#define PAIR_INSERT(accX, accY, sA, sB, CTB)                                 \
  {                                                                          \
    const int ctb_ = (CTB);                                                  \
    _Pragma("unroll") for (int r = 0; r < 4; ++r) {                          \
      float kA = fmaf((accX)[r], -2.0f, (sA));                               \
      float kB = fmaf((accY)[r], -2.0f, (sB));                               \
      int va = (__float_as_int(kA) & ~255) | ctb_;                           \
      int vb = (__float_as_int(kB) & ~255) | (ctb_ + 1);                     \
      int lo = min(va, vb), hi = max(va, vb);                                \
      int o0 = min(dl[r][0], lo);                                            \
      int o1 = min(min(dl[r][1], max(dl[r][0], lo)), hi);                    \
      int o2 = min(min(dl[r][2], max(dl[r][1], lo)), max(dl[r][0], hi));     \
      int o3 = min(min(dl[r][3], max(dl[r][2], lo)), max(dl[r][1], hi));     \
      int o4 = min(min(dl[r][4], max(dl[r][3], lo)), max(dl[r][2], hi));     \
      int o5 = min(min(dl[r][5], max(dl[r][4], lo)), max(dl[r][3], hi));     \
      int o6 = min(min(dl[r][6], max(dl[r][5], lo)), max(dl[r][4], hi));     \
      int o7 = min(min(dl[r][7], max(dl[r][6], lo)), max(dl[r][5], hi));     \
      dl[r][0] = o0; dl[r][1] = o1; dl[r][2] = o2; dl[r][3] = o3;            \
      dl[r][4] = o4; dl[r][5] = o5; dl[r][6] = o6; dl[r][7] = o7;            \
    }                                                                        \
  }

  int c0 = split * (N_ / NSPLIT);
  const _Float16* gpanel = xt16 + (bbase + c0) * 64;
  const float* spanel = sq + bbase + c0;

  // per-lane pre-swizzled source offset (bytes): LDS slot (r=lane>>3,
  // e=lane&7) receives global chunk e^(r&7) of row r.
  int soff = (lane >> 3) * 128 + (((lane & 7) ^ ((lane >> 3) & 7)) << 4);
  // per-lane read offsets (bytes, within a tile): content (row=col,
  // chunk q) lives at col*128 + (q^(col&7))*16. Second k-half = ^64.
  int rbo0 = col * 128 + (((quad) ^ (col & 7)) << 4);
  int rbo1 = rbo0 ^ 64;

#define STAGE(BUF, CH)                                                     \
  {                                                                        \
    const char* gt =                                                       \
        (const char*)gpanel + ((size_t)(CH)*64 + wave * 16) * 128;         \
    char* wb = &bufB[BUF][wave * 2048];                                    \
    GLOAD16(gt + soff, wb);                                                \
    GLOAD16(gt + 1024 + soff, wb + 1024);                                  \
    if (wave == 0) GLOAD4(spanel + (CH)*64 + lane, bufS[BUF]);             \
  }
#define CONSUME(BUF, CH)                                                   \
  {                                                                        \
    const char* lb = bufB[BUF];                                            \
    const float* sb = bufS[BUF];                                           \
    const f32x4 z = {0.f, 0.f, 0.f, 0.f};                                  \
    half8 F0 = *(const half8*)(lb + 0 * 2048 + rbo0);                      \
    half8 F1 = *(const half8*)(lb + 0 * 2048 + rbo1);                      \
    half8 G0 = *(const half8*)(lb + 1 * 2048 + rbo0);                      \
    half8 G1 = *(const half8*)(lb + 1 * 2048 + rbo1);                      \
    f32x4 a0 = __builtin_amdgcn_mfma_f32_16x16x32_f16(A0, F0, z, 0, 0, 0); \
    a0 = __builtin_amdgcn_mfma_f32_16x16x32_f16(A1, F1, a0, 0, 0, 0);      \
    f32x4 a1 = __builtin_amdgcn_mfma_f32_16x16x32_f16(A0, G0, z, 0, 0, 0); \
    a1 = __builtin_amdgcn_mfma_f32_16x16x32_f16(A1, G1, a1, 0, 0, 0);      \
    half8 H0 = *(const half8*)(lb + 2 * 2048 + rbo0);                      \
    half8 H1 = *(const half8*)(lb + 2 * 2048 + rbo1);                      \
    half8 I0 = *(const half8*)(lb + 3 * 2048 + rbo0);                      \
    half8 I1 = *(const half8*)(lb + 3 * 2048 + rbo1);                      \
    f32x4 a2 = __builtin_amdgcn_mfma_f32_16x16x32_f16(A0, H0, z, 0, 0, 0); \
    a2 = __builtin_amdgcn_mfma_f32_16x16x32_f16(A1, H1, a2, 0, 0, 0);      \
    f32x4 a3 = __builtin_amdgcn_mfma_f32_16x16x32_f16(A0, I0, z, 0, 0, 0); \
    a3 = __builtin_amdgcn_mfma_f32_16x16x32_f16(A1, I1, a3, 0, 0, 0);      \
    float s0 = sb[col], s1 = sb[16 + col];                                 \
    float s2 = sb[32 + col], s3 = sb[48 + col];                            \
    PAIR_INSERT(a0, a1, s0, s1, (CH)*4);                                   \
    PAIR_INSERT(a2, a3, s2, s3, (CH)*4 + 2);                               \
  }

  // prologue: stage chunk0 -> buf0; barrier drains gload_lds (vmcnt(0))
  STAGE(0, 0);
  __syncthreads();

  for (int ch = 0; ch < 32; ch += 2) {
    STAGE(1, ch + 1);     // buf1 last read at previous iteration's end-barrier
    CONSUME(0, ch);
    __syncthreads();      // buf1 ready; all waves done reading buf0
    if (ch + 2 < 32) STAGE(0, ch + 2);
    CONSUME(1, ch + 1);
    __syncthreads();      // buf0 ready; all waves done reading buf1
  }
#undef PAIR_INSERT
#undef STAGE
#undef CONSUME

#pragma unroll
  for (int r = 0; r < 4; ++r) {
    int q = q0 + quad * 4 + r;
    int* o = pidx + (bbase + q) * NCAND + split * (16 * LCELL) + col * LCELL;
#pragma unroll
    for (int j = 0; j < LCELL; ++j) o[j] = dl[r][j];  // raw packed value
  }
}

// ---- Kernel 3: refinement v11 (R8 WIN, unchanged) — short-chain pops,
// two points per wave, DPP min-reduce, ballot-decoded indices (no slds).
__global__ __launch_bounds__(256) void refine_kernel(
    const float* __restrict__ xt, const double* __restrict__ sqd,
    const int* __restrict__ pidx, int* __restrict__ idxf) {
  __shared__ float qs[4][2][64];
  __shared__ double klds[4][2][32];
  int tid = threadIdx.x;
  int wave = tid >> 6, lane = tid & 63;
  int pA = blockIdx.x * 8 + wave * 2;  // even global point id
  int pB = pA + 1;
  int b = pA >> 13;  // pA,pB share batch (8-aligned block of points)
  size_t bbase = (size_t)b * N_;
  int plA = pA & (N_ - 1), plB = pB & (N_ - 1);

  // stage both query rows into LDS (lanes 0..15 -> A, 16..31 -> B)
  if (lane < 16) {
    ((f32x4*)qs[wave][0])[lane] = ((const f32x4*)(xt + (size_t)pA * 64))[lane];
  } else if (lane < 32) {
    int l = lane - 16;
    ((f32x4*)qs[wave][1])[l] = ((const f32x4*)(xt + (size_t)pB * 64))[l];
  }

  // stage 1: lane's cell (split=lane>>4, col=lane&15): 8 sorted values per
  // point. Self-exclude (single displacement -> one bubble pass each).
  const int* piA = pidx + (size_t)pA * NCAND + lane * 8;
  const int* piB = pidx + (size_t)pB * NCAND + lane * 8;
  int4 ca0 = *(const int4*)piA;
  int4 ca1 = *(const int4*)(piA + 4);
  int4 cb0 = *(const int4*)piB;
  int4 cb1 = *(const int4*)(piB + 4);
  int colsplit = (lane & 15) + (lane >> 4) * (N_ / NSPLIT);

  int uA0 = ca0.x, uA1 = ca0.y, uA2 = ca0.z, uA3 = ca0.w;
  int uA4 = ca1.x, uA5 = ca1.y, uA6 = ca1.z, uA7 = ca1.w;
  int uB0 = cb0.x, uB1 = cb0.y, uB2 = cb0.z, uB3 = cb0.w;
  int uB4 = cb1.x, uB5 = cb1.y, uB6 = cb1.z, uB7 = cb1.w;
#define EXCL(v, pl) if (((((v)&255) << 4) + colsplit) == (pl)) (v) = 0x7fffffff;
  EXCL(uA0, plA) EXCL(uA1, plA) EXCL(uA2, plA) EXCL(uA3, plA)
  EXCL(uA4, plA) EXCL(uA5, plA) EXCL(uA6, plA) EXCL(uA7, plA)
  EXCL(uB0, plB) EXCL(uB1, plB) EXCL(uB2, plB) EXCL(uB3, plB)
  EXCL(uB4, plB) EXCL(uB5, plB) EXCL(uB6, plB) EXCL(uB7, plB)
#undef EXCL
#define BUB(a, b_) { int lo_ = min(a, b_), hi_ = max(a, b_); a = lo_; b_ = hi_; }
  BUB(uA0, uA1) BUB(uA1, uA2) BUB(uA2, uA3) BUB(uA3, uA4)
  BUB(uA4, uA5) BUB(uA5, uA6) BUB(uA6, uA7)
  BUB(uB0, uB1) BUB(uB1, uB2) BUB(uB2, uB3) BUB(uB3, uB4)
  BUB(uB4, uB5) BUB(uB5, uB6) BUB(uB6, uB7)
#undef BUB

  // stage 2: 32 pops per chain, interleaved; ci decoded from ballot (no LDS)
  unsigned long long mylt = (1ull << lane) - 1;
  int myci = 0;
#pragma unroll
  for (int s = 0; s < 32; ++s) {
    int mA = wave_min_i32(uA0);
    int mB = wave_min_i32(uB0);
    bool eqA = (uA0 == mA);
    bool eqB = (uB0 == mB);
    unsigned long long balA = __ballot(eqA);
    unsigned long long balB = __ballot(eqB);
    int ownA = (int)__builtin_ctzll(balA);
    int ownB = (int)__builtin_ctzll(balB);
    int ciA = ((mA & 255) << 4) + (ownA & 15) + (ownA >> 4) * (N_ / NSPLIT);
    int ciB = ((mB & 255) << 4) + (ownB & 15) + (ownB >> 4) * (N_ / NSPLIT);
    if (lane == s) myci = ciA;
    if (lane == s + 32) myci = ciB;
    bool advA = eqA && ((balA & mylt) == 0);  // first owner pops chain A
    bool advB = eqB && ((balB & mylt) == 0);
    uA0 = advA ? uA1 : uA0; uA1 = advA ? uA2 : uA1;
    uA2 = advA ? uA3 : uA2; uA3 = advA ? uA4 : uA3;
    uA4 = advA ? uA5 : uA4; uA5 = advA ? uA6 : uA5;
    uA6 = advA ? uA7 : uA6; uA7 = advA ? 0x7fffffff : uA7;
    uB0 = advB ? uB1 : uB0; uB1 = advB ? uB2 : uB1;
    uB2 = advB ? uB3 : uB2; uB3 = advB ? uB4 : uB3;
    uB4 = advB ? uB5 : uB4; uB5 = advB ? uB6 : uB5;
    uB6 = advB ? uB7 : uB6; uB7 = advB ? 0x7fffffff : uB7;
  }

  // stage 3: lane<32 -> point A candidate lane; lane>=32 -> point B
  // candidate lane-32. Full 64-dim fp64 dot per lane (4 accums).
  int half = lane >> 5;
  int s32 = lane & 31;
  int ci = myci;
  const f32x4* cr = (const f32x4*)(xt + (bbase + ci) * 64);
  const f32x4* qr = (const f32x4*)qs[wave][half];
  double a0 = 0.0, a1 = 0.0, a2 = 0.0, a3 = 0.0;
#pragma unroll
  for (int t2 = 0; t2 < 16; ++t2) {
    f32x4 cv = cr[t2];
    f32x4 qv = qr[t2];  // ds_read_b128 broadcast within each half
    a0 = fma((double)cv.x, (double)qv.x, a0);
    a1 = fma((double)cv.y, (double)qv.y, a1);
    a2 = fma((double)cv.z, (double)qv.z, a2);
    a3 = fma((double)cv.w, (double)qv.w, a3);
  }
  double dot = (a0 + a1) + (a2 + a3);
  double kd = fma(dot, -2.0, sqd[bbase + ci]) + 1024.0;
  double kv = __longlong_as_double(
      (__double_as_longlong(kd) & ~0x1FFFLL) | (long long)ci);
  klds[wave][half][s32] = kv;

  // stage 4: rank-count over own half's 32 unique exact keys
  {
    const double* kl = klds[wave][half];
    int c0 = 0, c1 = 0, c2 = 0, c3 = 0;
#pragma unroll
    for (int t2 = 0; t2 < 32; t2 += 4) {
      c0 += (kl[t2] < kv) ? 1 : 0;
      c1 += (kl[t2 + 1] < kv) ? 1 : 0;
      c2 += (kl[t2 + 2] < kv) ? 1 : 0;
      c3 += (kl[t2 + 3] < kv) ? 1 : 0;
    }
    int rank = (c0 + c1) + (c2 + c3);
    int pdst = half ? pB : pA;
    if (rank < K_) idxf[(size_t)pdst * K_ + rank] = ci;
  }
}

// ---- Kernel 4: stats v2 (R9 WIN, unchanged) — 1-deep gather pipeline
// across the 4 points (double-buffered G regs; next point's L2 latency
// hides under the current reduce).
__global__ __launch_bounds__(256) void stats_kernel(
    const float* __restrict__ y1, const float* __restrict__ y2,
    const int* __restrict__ idxf, float* __restrict__ maxh,
    float* __restrict__ minh, float* __restrict__ gsum,
    float* __restrict__ gsq) {
  __shared__ float lsum[64], lsq[64];
  int tid = threadIdx.x;
  if (tid < 64) { lsum[tid] = 0.f; lsq[tid] = 0.f; }
  __syncthreads();
  int wv = tid >> 6, lane = tid & 63;
  int u = lane & 15, jb = lane >> 4;
  int p0 = blockIdx.x * 16 + wv * 4;  // 16 contiguous points per block
  size_t nb = (size_t)((p0 >> 13) * N_);
  f32x4 css = {0.f, 0.f, 0.f, 0.f}, cqq = {0.f, 0.f, 0.f, 0.f};

  // preload all 4 points' neighbor indices (independent loads)
  int idxv0 = (lane < K_) ? idxf[(size_t)(p0 + 0) * K_ + lane] : 0;
  int idxv1 = (lane < K_) ? idxf[(size_t)(p0 + 1) * K_ + lane] : 0;
  int idxv2 = (lane < K_) ? idxf[(size_t)(p0 + 2) * K_ + lane] : 0;
  int idxv3 = (lane < K_) ? idxf[(size_t)(p0 + 3) * K_ + lane] : 0;

  f32x4 Ga0, Ga1, Ga2, Ga3, Ga4;  // buffer A
  f32x4 Gb0, Gb1, Gb2, Gb3, Gb4;  // buffer B

#define ISSUE(B0_, B1_, B2_, B3_, B4_, IV)                                 \
  {                                                                        \
    int n0 = __shfl((IV), jb, 64);                                         \
    int n1 = __shfl((IV), jb + 4, 64);                                     \
    int n2 = __shfl((IV), jb + 8, 64);                                     \
    int n3 = __shfl((IV), jb + 12, 64);                                    \
    int n4 = __shfl((IV), jb + 16, 64);                                    \
    B0_ = ((const f32x4*)(y1 + (nb + n0) * 64))[u];                        \
    B1_ = ((const f32x4*)(y1 + (nb + n1) * 64))[u];                        \
    B2_ = ((const f32x4*)(y1 + (nb + n2) * 64))[u];                        \
    B3_ = ((const f32x4*)(y1 + (nb + n3) * 64))[u];                        \
    B4_ = ((const f32x4*)(y1 + (nb + n4) * 64))[u];                        \
  }
#define REDUCE(B0_, B1_, B2_, B3_, B4_, IT)                                \
  {                                                                        \
    int p = p0 + (IT);                                                     \
    f32x4 mx = B0_, mn = B0_, sm = B0_, s2 = B0_ * B0_;                    \
    mx = max4(mx, B1_); mn = min4(mn, B1_); sm += B1_; s2 += B1_ * B1_;    \
    mx = max4(mx, B2_); mn = min4(mn, B2_); sm += B2_; s2 += B2_ * B2_;    \
    mx = max4(mx, B3_); mn = min4(mn, B3_); sm += B3_; s2 += B3_ * B3_;    \
    mx = max4(mx, B4_); mn = min4(mn, B4_); sm += B4_; s2 += B4_ * B4_;    \
    _Pragma("unroll") for (int c = 0; c < 4; ++c) {                        \
      mx[c] = fmaxf(mx[c], __shfl_xor(mx[c], 16, 64));                     \
      mx[c] = fmaxf(mx[c], __shfl_xor(mx[c], 32, 64));                     \
      mn[c] = fminf(mn[c], __shfl_xor(mn[c], 16, 64));                     \
      mn[c] = fminf(mn[c], __shfl_xor(mn[c], 32, 64));                     \
      sm[c] += __shfl_xor(sm[c], 16, 64);                                  \
      sm[c] += __shfl_xor(sm[c], 32, 64);                                  \
      s2[c] += __shfl_xor(s2[c], 16, 64);                                  \
      s2[c] += __shfl_xor(s2[c], 32, 64);                                  \
    }                                                                      \
    if (jb == 0) {                                                         \
      f32x4 y2c = ((const f32x4*)(y2 + (size_t)p * 64))[u];                \
      ((f32x4*)(maxh + (size_t)p * 64))[u] = mx + y2c;                     \
      ((f32x4*)(minh + (size_t)p * 64))[u] = mn + y2c;                     \
      css += sm + 20.0f * y2c;                                             \
      cqq += s2 + 2.0f * y2c * sm + 20.0f * y2c * y2c;                     \
    }                                                                      \
  }

  ISSUE(Ga0, Ga1, Ga2, Ga3, Ga4, idxv0);        // point 0 -> A
  ISSUE(Gb0, Gb1, Gb2, Gb3, Gb4, idxv1);        // point 1 -> B (in flight)
  REDUCE(Ga0, Ga1, Ga2, Ga3, Ga4, 0);           // reduce 0 (hides 1's lat)
  ISSUE(Ga0, Ga1, Ga2, Ga3, Ga4, idxv2);        // point 2 -> A
  REDUCE(Gb0, Gb1, Gb2, Gb3, Gb4, 1);           // reduce 1 (hides 2's lat)
  ISSUE(Gb0, Gb1, Gb2, Gb3, Gb4, idxv3);        // point 3 -> B
  REDUCE(Ga0, Ga1, Ga2, Ga3, Ga4, 2);           // reduce 2 (hides 3's lat)
  REDUCE(Gb0, Gb1, Gb2, Gb3, Gb4, 3);           // reduce 3
#undef ISSUE
#undef REDUCE

  if (jb == 0) {
#pragma unroll
    for (int c = 0; c < 4; ++c) {
      atomicAdd(&lsum[u * 4 + c], css[c]);
      atomicAdd(&lsq[u * 4 + c], cqq[c]);
    }
  }
  __syncthreads();
  if (tid < 64) {
    atomicAdd(&gsum[tid], lsum[tid]);
    atomicAdd(&gsq[tid], lsq[tid]);
  }
}

// ---- Kernel 5: affine + relu + max-over-k selection, transposed store.
// v2: pointer-select (single load) instead of ternary over two loads.
__global__ __launch_bounds__(256) void final_kernel(
    const float* __restrict__ maxh, const float* __restrict__ minh,
    const float* __restrict__ gsum, const float* __restrict__ gsq,
    const float* __restrict__ gamma, const float* __restrict__ beta,
    float* __restrict__ out) {
  __shared__ float sc[64], cc_[64];
  __shared__ float tile[64 * 65];
  int b = blockIdx.x >> 7;
  int n0 = (blockIdx.x & 127) * 64;
  int t = threadIdx.x;
  if (t < 64) {
    float mean = gsum[t] * (1.0f / CNT_TOTAL);
    float var = gsq[t] * (1.0f / CNT_TOTAL) - mean * mean;
    float s = gamma[t] * rsqrtf(var + BN_EPSF);
    sc[t] = s;
    cc_[t] = beta[t] - mean * s;
  }
  __syncthreads();
#pragma unroll
  for (int i = 0; i < 16; ++i) {
    int lin = i * 256 + t;
    int o = lin & 63, nl = lin >> 6;
    size_t off = ((size_t)(b * N_) + n0 + nl) * 64 + o;
    float s = sc[o];
    const float* src = (s >= 0.f) ? maxh : minh;  // pointer select, 1 load
    float val = fmaxf(fmaf(src[off], s, cc_[o]), 0.f);
    tile[o * 65 + nl] = val;
  }
  __syncthreads();
#pragma unroll
  for (int i = 0; i < 16; ++i) {
    int lin = i * 256 + t;
    int nl = lin & 63, o = lin >> 6;
    out[((size_t)(b * 64) + o) * N_ + n0 + nl] = tile[o * 65 + nl];
  }
}

extern "C" void kernel_launch(void* const* d_in, const int* in_sizes, int n_in,
                              void* d_out, int out_size, void* d_ws,
                              size_t ws_size, hipStream_t stream) {
  const float* x = (const float*)d_in[0];
  const float* W = (const float*)d_in[1];
  const float* gamma = (const float*)d_in[2];
  const float* beta = (const float*)d_in[3];
  float* out = (float*)d_out;

  char* ws = (char*)d_ws;
  size_t off = 0;
  auto alloc = [&](size_t bytes) {
    char* p = ws + off;
    off += (bytes + 255) & ~(size_t)255;
    return p;
  };
  float* xt = (float*)alloc((size_t)B_ * N_ * 64 * 4);
  _Float16* xt16 = (_Float16*)alloc((size_t)B_ * N_ * 64 * 2);
  float* y1 = (float*)alloc((size_t)B_ * N_ * 64 * 4);
  float* y2 = (float*)alloc((size_t)B_ * N_ * 64 * 4);
  float* sq = (float*)alloc((size_t)B_ * N_ * 4);
  double* sqd = (double*)alloc((size_t)B_ * N_ * 8);
  int* pidx = (int*)alloc((size_t)B_ * N_ * NCAND * 4);  // 67 MB
  float* maxh = (float*)alloc((size_t)B_ * N_ * 64 * 4);
  int* idxf = (int*)alloc((size_t)B_ * N_ * K_ * 4);
  float* gsum = (float*)alloc(256);
  float* gsq = (float*)alloc(256);
  // minh aliases pidx (pidx fully consumed by refine before stats runs)
  float* minh = (float*)pidx;

  hipMemsetAsync(gsum, 0, 256, stream);
  hipMemsetAsync(gsq, 0, 256, stream);

  prep_kernel<<<B_ * (N_ / 64), 256, 0, stream>>>(x, W, xt, xt16, sq, sqd,
                                                  y1, y2);
  knn_mfma_kernel<<<B_ * (N_ / 64) * NSPLIT, 256, 0, stream>>>(xt16, sq, pidx);
  refine_kernel<<<(B_ * N_) / 8, 256, 0, stream>>>(xt, sqd, pidx, idxf);
  stats_kernel<<<(B_ * N_) / 16, 256, 0, stream>>>(y1, y2, idxf, maxh, minh,
                                                   gsum, gsq);
  final_kernel<<<B_ * (N_ / 64), 256, 0, stream>>>(maxh, minh, gsum, gsq,
                                                   gamma, beta, out);
}